// Round 3
// baseline (354.213 us; speedup 1.0000x reference)
//
#include <hip/hip_runtime.h>

// TPlanesEnc: B=4, N=131072, P=512, F=32
// coords: [B*N, 3] f32 in [-1,1]; tplanes: [3, P, P, F] f32; out: [B*N, 3*F] f32
//
// Mapping: 8 lanes per (point, plane); lane handles one float4 of the F=32
// features. Texel rows are 128B contiguous -> 8-lane float4 reads are fully
// coalesced. Output per point is 96 contiguous f32 -> coalesced float4 stores.
//
// This version: PERSISTENT grid (2048 blocks = 256 CU x 8 resident blocks).
// Previous grid of 3072 blocks vs 2048 resident ran 1 full round + 1 half
// round -> measured OccupancyPercent was exactly 75%. In a miss-queue
// (concurrency) bound gather, the half-empty round runs at half throughput.
// Grid-stride loop (12 iters x 2 items) keeps all CUs full for the whole
// dispatch; next iteration's coords/addresses are prepped while current
// texel loads are in flight.

#define PS 512
#define FDIM 32

typedef float floatx4 __attribute__((ext_vector_type(4)));

struct Item {
    const floatx4* base;
    int o00, o01, o10, o11;
    float fx, fy;
    int oidx;
    bool valid;
};

__device__ __forceinline__ Item prep(int idx, int total,
                                     const float* __restrict__ coords,
                                     const float* __restrict__ tplanes)
{
    Item it;
    it.valid = (idx < total);
    it.oidx  = idx;
    int safe = it.valid ? idx : 0;      // avoid OOB, keep lanes convergent

    int chunk = safe & 7;               // FDIM/4 = 8 chunks
    int pp    = safe >> 3;              // (point, plane) pair
    int plane = pp % 3;
    int point = pp / 3;

    // [-1,1] -> [0,1]
    float cx = coords[point * 3 + 0] * 0.5f + 0.5f;
    float cy = coords[point * 3 + 1] * 0.5f + 0.5f;
    float cz = coords[point * 3 + 2] * 0.5f + 0.5f;

    // plane 0: (x,y); plane 1: (x,z); plane 2: (z,y)
    float u = (plane == 2) ? cz : cx;
    float v = (plane == 1) ? cz : cy;

    float x = fminf(fmaxf(u * (float)PS - 0.5f, 0.0f), (float)(PS - 1));
    float y = fminf(fmaxf(v * (float)PS - 0.5f, 0.0f), (float)(PS - 1));
    float x0f = floorf(x);
    float y0f = floorf(y);
    int xi0 = (int)x0f;
    int yi0 = (int)y0f;
    int xi1 = min(xi0 + 1, PS - 1);
    int yi1 = min(yi0 + 1, PS - 1);
    it.fx = x - x0f;
    it.fy = y - y0f;

    it.base = (const floatx4*)(tplanes + (size_t)plane * PS * PS * FDIM);
    // float4 index of texel row (y, x): (y*PS + x)*8
    it.o00 = (yi0 * PS + xi0) * 8 + chunk;
    it.o01 = (yi0 * PS + xi1) * 8 + chunk;
    it.o10 = (yi1 * PS + xi0) * 8 + chunk;
    it.o11 = (yi1 * PS + xi1) * 8 + chunk;
    return it;
}

__device__ __forceinline__ void finish(const Item& it,
                                       floatx4 f00, floatx4 f01,
                                       floatx4 f10, floatx4 f11,
                                       float* __restrict__ out)
{
    if (!it.valid) return;
    float fx = it.fx, fy = it.fy;
    float gx = 1.0f - fx;
    float gy = 1.0f - fy;
    floatx4 r;
    r.x = (f00.x * gx + f01.x * fx) * gy + (f10.x * gx + f11.x * fx) * fy;
    r.y = (f00.y * gx + f01.y * fx) * gy + (f10.y * gx + f11.y * fx) * fy;
    r.z = (f00.z * gx + f01.z * fx) * gy + (f10.z * gx + f11.z * fx) * fy;
    r.w = (f00.w * gx + f01.w * fx) * gy + (f10.w * gx + f11.w * fx) * fy;
    __builtin_nontemporal_store(r, (floatx4*)out + it.oidx);
}

__global__ __launch_bounds__(256) void tplanes_enc_kernel(
    const float* __restrict__ coords,   // [M, 3]
    const float* __restrict__ tplanes,  // [3, PS, PS, FDIM]
    float* __restrict__ out,            // [M, 3*FDIM]
    int total, int stride)              // stride = gridDim.x * blockDim.x
{
    int tid = blockIdx.x * blockDim.x + threadIdx.x;

    // Prologue: prep first pair of items.
    Item a = prep(tid,          total, coords, tplanes);
    Item b = prep(tid + stride, total, coords, tplanes);

    for (int i = tid; i < total; ) {
        // Phase 1: issue all 8 texel loads for the current pair.
        floatx4 a00{}, a01{}, a10{}, a11{};
        floatx4 b00{}, b01{}, b10{}, b11{};
        if (a.valid) {
            a00 = a.base[a.o00]; a01 = a.base[a.o01];
            a10 = a.base[a.o10]; a11 = a.base[a.o11];
        }
        if (b.valid) {
            b00 = b.base[b.o00]; b01 = b.base[b.o01];
            b10 = b.base[b.o10]; b11 = b.base[b.o11];
        }

        // Phase 2: prep next iteration (coord loads + VALU hide under
        // the outstanding texel misses).
        int ni = i + 2 * stride;
        Item na = prep(ni,          total, coords, tplanes);
        Item nb = prep(ni + stride, total, coords, tplanes);

        // Phase 3: consume texels, bilerp, nontemporal store.
        finish(a, a00, a01, a10, a11, out);
        finish(b, b00, b01, b10, b11, out);

        a = na; b = nb; i = ni;
    }
}

extern "C" void kernel_launch(void* const* d_in, const int* in_sizes, int n_in,
                              void* d_out, int out_size, void* d_ws, size_t ws_size,
                              hipStream_t stream) {
    const float* coords  = (const float*)d_in[0];
    const float* tplanes = (const float*)d_in[1];
    float* out = (float*)d_out;

    int M = in_sizes[0] / 3;            // B*N points
    int total = M * 3 * (FDIM / 4);     // one item per float4 chunk (12.58M)
    int block = 256;
    // Persistent grid: 256 CUs x 8 resident blocks of 256 threads.
    int grid  = 2048;
    int stride = grid * block;          // 524288; 12.58M / (2*stride) = 12 iters
    tplanes_enc_kernel<<<grid, block, 0, stream>>>(coords, tplanes, out, total, stride);
}